// Round 10
// baseline (271.372 us; speedup 1.0000x reference)
//
#include <hip/hip_runtime.h>

typedef unsigned short u16;
typedef __attribute__((ext_vector_type(8))) __bf16 bf16x8;
typedef __attribute__((ext_vector_type(8))) unsigned short u16x8;
typedef __attribute__((ext_vector_type(4))) float f32x4;

__device__ __forceinline__ float bf2f(u16 h) {
    return __uint_as_float(((unsigned int)h) << 16);
}
__device__ __forceinline__ u16 f2bf(float f) {
    unsigned int u = __float_as_uint(f);
    u += 0x7fffu + ((u >> 16) & 1u);   // round-to-nearest-even
    return (u16)(u >> 16);
}
__device__ __forceinline__ bf16x8 zero_bf16x8() {
    union { unsigned int u[4]; bf16x8 v; } z;
    z.u[0] = z.u[1] = z.u[2] = z.u[3] = 0u;
    return z.v;
}
__device__ __forceinline__ void gload_lds16(const void* g, void* l) {
    __builtin_amdgcn_global_load_lds(
        (const __attribute__((address_space(1))) unsigned int*)g,
        (__attribute__((address_space(3))) unsigned int*)l, 16, 0, 0);
}
__device__ __forceinline__ void store_out(u16* p, float v)  { *p = f2bf(v); }
__device__ __forceinline__ void store_out(float* p, float v){ *p = v; }

// ================= fused pre-pass (1 launch) =================

__device__ __forceinline__ void do_cvt(
    const float* __restrict__ in, u16* __restrict__ out, int blk)
{
    int i = (blk * 256 + (int)threadIdx.x) * 8;
    float4 a = *(const float4*)(in + i);
    float4 b = *(const float4*)(in + i + 4);
    u16x8 o;
    o[0] = f2bf(a.x); o[1] = f2bf(a.y); o[2] = f2bf(a.z); o[3] = f2bf(a.w);
    o[4] = f2bf(b.x); o[5] = f2bf(b.y); o[6] = f2bf(b.z); o[7] = f2bf(b.w);
    *(u16x8*)(out + i) = o;
}

__device__ __forceinline__ void do_transpose(
    const float* __restrict__ in, u16* __restrict__ out, int K, int F, int t)
{
    __shared__ u16 tt[32][33];
    int fb = t % (F >> 5), kb = t / (F >> 5);
    int f0 = fb << 5, k0 = kb << 5;
    int lx = threadIdx.x & 31;
    int ly = threadIdx.x >> 5;
#pragma unroll
    for (int i = 0; i < 4; ++i) {
        int k = ly + i * 8;
        tt[k][lx] = f2bf(in[(size_t)(k0 + k) * F + f0 + lx]);
    }
    __syncthreads();
#pragma unroll
    for (int i = 0; i < 4; ++i) {
        int fy = ly + i * 8;
        out[(size_t)(f0 + fy) * K + k0 + lx] = tt[lx][fy];
    }
}

__device__ __forceinline__ void do_prep_d(
    const float* __restrict__ d, u16* __restrict__ o, int K, int blk)
{
    int i = blk * 256 + (int)threadIdx.x;
    int r = i & 7;
    int k = (i >> 3) % K;
    int t = i / (K * 8);
    o[i] = f2bf(d[((size_t)k * 8 + r) * 8 + t]);
}

__device__ __forceinline__ void do_prep_u(
    const float* __restrict__ u, u16* __restrict__ o, int F, int blk)
{
    int i = blk * 256 + (int)threadIdx.x;
    int r = i & 7;
    int f = (i >> 3) % F;
    int t = i / (F * 8);
    o[i] = f2bf(u[((size_t)r * F + f) * 8 + t] * 2.0f);
}

__global__ __launch_bounds__(256) void prep_all(
    const float* x, const float* k0, const float* k1, const float* k2,
    const float* d0, const float* d1, const float* d2,
    const float* u0, const float* u1, const float* u2,
    u16* xb, u16* k0T, u16* k1T, u16* k2T,
    u16* dS0, u16* dS1, u16* dS2, u16* uS0, u16* uS1, u16* uS2)
{
    int b = blockIdx.x;
    if      (b < 4096)  do_cvt(x, xb, b);
    else if (b < 6144)  do_transpose(k0, k0T, 1024, 2048, b - 4096);
    else if (b < 10240) do_transpose(k1, k1T, 2048, 2048, b - 6144);
    else if (b < 12288) do_transpose(k2, k2T, 2048, 1024, b - 10240);
    else if (b < 12544) do_prep_d(d0, dS0, 1024, b - 12288);
    else if (b < 13056) do_prep_d(d1, dS1, 2048, b - 12544);
    else if (b < 13568) do_prep_d(d2, dS2, 2048, b - 13056);
    else if (b < 14080) do_prep_u(u0, uS0, 2048, b - 13568);
    else if (b < 14592) do_prep_u(u1, uS1, 2048, b - 14080);
    else                do_prep_u(u2, uS2, 1024, b - 14592);
}

// ---------------- LoRA down-projection (unchanged) ----------------
__global__ __launch_bounds__(256) void lora_down(
    const u16* __restrict__ H, const u16* __restrict__ dS,
    u16* __restrict__ Aout, int K)
{
    int gt   = blockIdx.x * 256 + threadIdx.x;
    int row  = gt >> 3;
    int oct  = gt & 7;
    int task = row >> 10;
    const u16* hrow = H  + (size_t)row * K;
    const u16* dt   = dS + (size_t)task * K * 8;
    float acc[8];
#pragma unroll
    for (int r = 0; r < 8; ++r) acc[r] = 0.f;
    int kpt  = K >> 3;
    int kbeg = oct * kpt;
    for (int kk = kbeg; kk < kbeg + kpt; kk += 8) {
        u16x8 h8 = *(const u16x8*)(hrow + kk);
#pragma unroll
        for (int j = 0; j < 8; ++j) {
            float hv = bf2f(h8[j]);
            u16x8 dv = *(const u16x8*)(dt + (size_t)(kk + j) * 8);
#pragma unroll
            for (int r = 0; r < 8; ++r)
                acc[r] += hv * bf2f(dv[r]);
        }
    }
#pragma unroll
    for (int r = 0; r < 8; ++r) {
        acc[r] += __shfl_xor(acc[r], 1);
        acc[r] += __shfl_xor(acc[r], 2);
        acc[r] += __shfl_xor(acc[r], 4);
    }
    if (oct == 0) {
        u16x8 o;
#pragma unroll
        for (int r = 0; r < 8; ++r) o[r] = f2bf(acc[r]);
        *(u16x8*)(Aout + (size_t)row * 8) = o;
    }
}

// ============ BMxBN 8-phase GEMM + rank-8 LoRA epilogue ===================
// R9 kernel + T5 setprio (single-variable change this round).
// T5 placement per m201 template: setprio(1) immediately before the MFMA
// cluster, setprio(0) immediately after. Mechanism (m218b): the 8-phase
// split creates {stage-issuing vs MFMA-entering} wave role diversity on the
// CU scheduler; boosting MFMA-phase waves keeps the matrix pipe fed.
// Everything else identical to R9 (proven: 0 conflicts, no spill, passed).
// Swizzle: logical 16B chunk kc of row r at physical slot kc^(r&7); stage via
// pre-swizzled global source; read slot=(ks*4+lg)^(l15&7) -> 8 lanes/slot.
// vmcnt: counted wait = loads of the 2 youngest phases = SAL+SBL
//   (BM,BN)=(256,256)->4 ; (128,256)->3. Hazard maps unchanged from R9.

#define WVMC do { if constexpr (SAL + SBL == 4) { \
                    asm volatile("s_waitcnt vmcnt(4)" ::: "memory"); \
                  } else { \
                    asm volatile("s_waitcnt vmcnt(3)" ::: "memory"); } } while (0)
#define WVM0  asm volatile("s_waitcnt vmcnt(0)" ::: "memory")
#define PHASE_END do { __builtin_amdgcn_sched_barrier(0); \
                       __builtin_amdgcn_s_barrier(); } while (0)
#define PRIO1 __builtin_amdgcn_s_setprio(1)
#define PRIO0 __builtin_amdgcn_s_setprio(0)

#define DS_A(c, mh) do { \
    _Pragma("unroll") for (int mm = 0; mm < NMH; ++mm) \
    _Pragma("unroll") for (int ks = 0; ks < 2; ++ks) \
        aF[mm][ks] = *(const bf16x8*)((const char*)&sA[c][0] + \
                       arowb + ((mh)*NMH+mm)*4096 + (ks ? cb1 : cb0)); } while (0)

#define DS_B(c, nh, bset) do { \
    _Pragma("unroll") for (int nn = 0; nn < NBH; ++nn) \
    _Pragma("unroll") for (int ks = 0; ks < 2; ++ks) \
        bset[nn][ks] = *(const bf16x8*)((const char*)&sB[c][0] + \
                       browb + ((nh)*NBH+nn)*8192 + (ks ? cb1 : cb0)); } while (0)

#define MFMAQ(mh, nh, bset) do { \
    _Pragma("unroll") for (int ks = 0; ks < 2; ++ks) \
    _Pragma("unroll") for (int mm = 0; mm < NMH; ++mm) \
    _Pragma("unroll") for (int nn = 0; nn < NBH; ++nn) \
        acc[(mh)*NMH+mm][(nh)*NBH+nn] = __builtin_amdgcn_mfma_f32_16x16x32_bf16( \
            aF[mm][ks], bset[nn][ks], acc[(mh)*NMH+mm][(nh)*NBH+nn], 0, 0, 0); } while (0)

#define STAGE_A(c, h, kt) do { \
    _Pragma("unroll") for (int s = 0; s < SAL; ++s) \
        gload_lds16((const char*)A + (size_t)(unsigned)(aBase + \
                      ((h)*BMH + s*64)*(K*2) + (kt)*128), \
                    (char*)&sA[c][0] + (h)*(BMH*128) + s*8192 + tdst); } while (0)

#define STAGE_B(c, h, kt) do { \
    _Pragma("unroll") for (int s = 0; s < SBL; ++s) \
        gload_lds16((const char*)BT + (size_t)(unsigned)(bBase + \
                      ((h)*BNH + s*64)*(K*2) + (kt)*128), \
                    (char*)&sB[c][0] + (h)*(BNH*128) + s*8192 + tdst); } while (0)

template<int RELU, int BM, int BN, typename OUT_T>
__global__ __launch_bounds__(512, 2) void gemm_lora8(
    const u16* __restrict__ A, const u16* __restrict__ BT,
    const u16* __restrict__ ALR, const u16* __restrict__ US,
    const float* __restrict__ bias, OUT_T* __restrict__ C,
    int N, int K)
{
    constexpr int SAL = BM / 128;   // stage loads/thread per A-half
    constexpr int SBL = BN / 128;   // stage loads/thread per B-half
    constexpr int NMH = BM / 64;    // 16-row m-blocks per wave per A-half
    constexpr int NMB = BM / 32;    // m-blocks per wave total
    constexpr int NBH = BN / 128;   // 16-col n-blocks per wave per B-half
    constexpr int NBN = BN / 64;    // n-blocks per wave total
    constexpr int BMH = BM / 2;     // rows per A-half
    constexpr int BNH = BN / 2;     // rows per B-half

    __shared__ __align__(16) u16 sA[2][BM * 64];
    __shared__ __align__(16) u16 sB[2][BN * 64];

    const int tid  = threadIdx.x;
    const int lane = tid & 63;
    const int wave = tid >> 6;
    const int wr   = wave >> 2;   // 0..1
    const int wc   = wave & 3;    // 0..3
    const int l15  = lane & 15;
    const int lg   = lane >> 4;

    // bijective XCD swizzle (m204)
    const int nwg = gridDim.x;
    const int orig = blockIdx.x;
    const int q = nwg >> 3, r = nwg & 7;
    const int x = orig & 7, o = orig >> 3;
    const int wg = (x < r ? x * (q + 1) : r * (q + 1) + (x - r) * q) + o;
    const int nbn  = N / BN;
    const int bm   = wg / nbn;
    const int bn   = wg % nbn;
    const int brow = bm * BM;
    const int bcol = bn * BN;
    const int task = brow >> 10;

    // staging addressing (kc independent of h,s: all half offsets == 0 mod 8)
    const int trow = tid >> 3;                       // 0..63
    const int tkc  = (tid & 7) ^ (trow & 7);
    const int tdst = tid * 16;
    const int aBase = (brow + trow) * (K * 2) + tkc * 16;
    const int bBase = (bcol + trow) * (K * 2) + tkc * 16;

    // ds_read column bases: slot = (ks*4+lg) ^ (l15&7)
    const int rp    = l15 & 7;
    const int cb0   = ((lg ^ (rp & 3)) << 4) | ((rp & 4) << 4);  // ks=0
    const int cb1   = cb0 ^ 64;                                   // ks=1
    const int arowb = (wr * 16 + l15) * 128;
    const int browb = (wc * 16 + l15) * 128;

    f32x4 acc[NMB][NBN];
    const f32x4 zf = {0.f, 0.f, 0.f, 0.f};
#pragma unroll
    for (int m = 0; m < NMB; ++m)
#pragma unroll
        for (int n = 0; n < NBN; ++n) acc[m][n] = zf;

    bf16x8 aF[NMH][2], bF0[NBH][2], bF1[NBH][2];

    // prologue: buf0 <- t0 (4 halves), buf1 <- t1 A0,B0
    STAGE_A(0, 0, 0); STAGE_B(0, 0, 0); STAGE_A(0, 1, 0); STAGE_B(0, 1, 0);
    STAGE_A(1, 0, 1); STAGE_B(1, 0, 1);
    WVMC;              // buf0 tile landed; buf1 A0,B0 stay in flight
    PHASE_END;

    const int iters = K >> 7;
#pragma unroll 1
    for (int i = 0; i < iters; ++i) {
        const int t1 = 2 * i + 1, t2 = 2 * i + 2, t3 = 2 * i + 3;
        const bool nl = (i + 1 < iters);

        // P0: quad(0,0) buf0 ; stage buf1.A1 <- t1
        STAGE_A(1, 1, t1);
        DS_A(0, 0); DS_B(0, 0, bF0);
        PRIO1; MFMAQ(0, 0, bF0); PRIO0;
        PHASE_END;
        // P1: quad(0,1) buf0 ; stage buf1.B1 <- t1
        STAGE_B(1, 1, t1);
        DS_B(0, 1, bF1);
        PRIO1; MFMAQ(0, 1, bF1); PRIO0;
        PHASE_END;
        // P2: quad(1,0) buf0 ; stage buf0.A0 <- t2
        if (nl) STAGE_A(0, 0, t2);
        DS_A(0, 1);
        PRIO1; MFMAQ(1, 0, bF0); PRIO0;
        PHASE_END;
        // P3: quad(1,1) buf0 ; stage buf0.B0 <- t2 ; counted vmcnt
        if (nl) STAGE_B(0, 0, t2);
        PRIO1; MFMAQ(1, 1, bF1); PRIO0;
        if (nl) { WVMC; } else { WVM0; }
        PHASE_END;
        // P4: quad(0,0) buf1 ; stage buf0.A1 <- t2
        if (nl) STAGE_A(0, 1, t2);
        DS_A(1, 0); DS_B(1, 0, bF0);
        PRIO1; MFMAQ(0, 0, bF0); PRIO0;
        PHASE_END;
        // P5: quad(0,1) buf1 ; stage buf0.B1 <- t2
        if (nl) STAGE_B(0, 1, t2);
        DS_B(1, 1, bF1);
        PRIO1; MFMAQ(0, 1, bF1); PRIO0;
        PHASE_END;
        // P6: quad(1,0) buf1 ; stage buf1.A0 <- t3
        if (nl) STAGE_A(1, 0, t3);
        DS_A(1, 1);
        PRIO1; MFMAQ(1, 0, bF0); PRIO0;
        PHASE_END;
        // P7: quad(1,1) buf1 ; stage buf1.B0 <- t3 ; counted vmcnt
        if (nl) STAGE_B(1, 0, t3);
        PRIO1; MFMAQ(1, 1, bF1); PRIO0;
        if (nl) { WVMC; } else { WVM0; }
        PHASE_END;
    }

    // rank-8 LoRA delta: one extra MFMA round (k 0..7 valid, lanes lg>0 zero)
    bf16x8 z8 = zero_bf16x8();
    bf16x8 bU[NBN];
#pragma unroll
    for (int n = 0; n < NBN; ++n) {
        int col = bcol + n * 64 + wc * 16 + l15;
        bU[n] = (lg == 0) ? *(const bf16x8*)(US + ((size_t)task * N + col) * 8) : z8;
    }
#pragma unroll
    for (int m = 0; m < NMB; ++m) {
        int row = brow + m * 32 + wr * 16 + l15;
        bf16x8 aL = (lg == 0) ? *(const bf16x8*)(ALR + (size_t)row * 8) : z8;
#pragma unroll
        for (int n = 0; n < NBN; ++n)
            acc[m][n] = __builtin_amdgcn_mfma_f32_16x16x32_bf16(
                aL, bU[n], acc[m][n], 0, 0, 0);
    }

    // bias (+ReLU) + store; C/D: col = lane&15, row = lg*4 + reg
#pragma unroll
    for (int n = 0; n < NBN; ++n) {
        int col  = bcol + n * 64 + wc * 16 + l15;
        float bv = bias[col];
#pragma unroll
        for (int m = 0; m < NMB; ++m) {
            int row0 = brow + m * 32 + wr * 16 + lg * 4;
#pragma unroll
            for (int rr = 0; rr < 4; ++rr) {
                float v = acc[m][n][rr] + bv;
                if (RELU) v = fmaxf(v, 0.0f);
                store_out(&C[(size_t)(row0 + rr) * N + col], v);
            }
        }
    }
}

// ---------------- launch ----------------

extern "C" void kernel_launch(void* const* d_in, const int* in_sizes, int n_in,
                              void* d_out, int out_size, void* d_ws, size_t ws_size,
                              hipStream_t stream) {
    const float* x  = (const float*)d_in[0];
    const float* k0 = (const float*)d_in[1];
    const float* b0 = (const float*)d_in[2];
    const float* d0 = (const float*)d_in[3];
    const float* u0 = (const float*)d_in[4];
    const float* k1 = (const float*)d_in[5];
    const float* b1 = (const float*)d_in[6];
    const float* d1 = (const float*)d_in[7];
    const float* u1 = (const float*)d_in[8];
    const float* k2 = (const float*)d_in[9];
    const float* b2 = (const float*)d_in[10];
    const float* d2 = (const float*)d_in[11];
    const float* u2 = (const float*)d_in[12];

    const int T = 8, B = 1024, D = 1024, H1 = 2048, H2 = 2048, H3 = 1024;
    const int M = T * B;

    u16* w = (u16*)d_ws;
    size_t off = 0;
    u16* xb  = w + off; off += (size_t)M * D;
    u16* k0T = w + off; off += (size_t)H1 * D;
    u16* k1T = w + off; off += (size_t)H2 * H1;
    u16* k2T = w + off; off += (size_t)H3 * H2;
    u16* dS0 = w + off; off += (size_t)T * D * 8;
    u16* dS1 = w + off; off += (size_t)T * H1 * 8;
    u16* dS2 = w + off; off += (size_t)T * H2 * 8;
    u16* uS0 = w + off; off += (size_t)T * H1 * 8;
    u16* uS1 = w + off; off += (size_t)T * H2 * 8;
    u16* uS2 = w + off; off += (size_t)T * H3 * 8;
    u16* h1  = w + off; off += (size_t)M * H1;
    u16* h2  = w + off; off += (size_t)M * H2;
    u16* Ab  = w + off; off += (size_t)M * 8;
    (void)ws_size; (void)in_sizes; (void)n_in; (void)out_size;

    prep_all<<<14848, 256, 0, stream>>>(
        x, k0, k1, k2, d0, d1, d2, u0, u1, u2,
        xb, k0T, k1T, k2T, dS0, dS1, dS2, uS0, uS1, uS2);

    // layer 0 (BM=256,BN=256: 32x8 = 256 blocks)
    lora_down<<<(M * 8) / 256, 256, 0, stream>>>(xb, dS0, Ab, D);
    gemm_lora8<1, 256, 256, u16><<<(M / 256) * (H1 / 256), 512, 0, stream>>>(
        xb, k0T, Ab, uS0, b0, h1, H1, D);
    // layer 1 (BM=256,BN=256: 32x8 = 256 blocks)
    lora_down<<<(M * 8) / 256, 256, 0, stream>>>(h1, dS1, Ab, H1);
    gemm_lora8<1, 256, 256, u16><<<(M / 256) * (H2 / 256), 512, 0, stream>>>(
        h1, k1T, Ab, uS1, b1, h2, H2, H1);
    // layer 2 (no relu, fp32 out; BM=128,BN=256: 64x4 = 256 blocks)
    lora_down<<<(M * 8) / 256, 256, 0, stream>>>(h2, dS2, Ab, H2);
    gemm_lora8<0, 128, 256, float><<<(M / 128) * (H3 / 256), 512, 0, stream>>>(
        h2, k2T, Ab, uS2, b2, (float*)d_out, H3, H2);
}

// Round 11
// 269.834 us; speedup vs baseline: 1.0057x; 1.0057x over previous
//
#include <hip/hip_runtime.h>

typedef unsigned short u16;
typedef __attribute__((ext_vector_type(8))) __bf16 bf16x8;
typedef __attribute__((ext_vector_type(8))) unsigned short u16x8;
typedef __attribute__((ext_vector_type(4))) float f32x4;

__device__ __forceinline__ float bf2f(u16 h) {
    return __uint_as_float(((unsigned int)h) << 16);
}
__device__ __forceinline__ u16 f2bf(float f) {
    unsigned int u = __float_as_uint(f);
    u += 0x7fffu + ((u >> 16) & 1u);   // round-to-nearest-even
    return (u16)(u >> 16);
}
__device__ __forceinline__ bf16x8 zero_bf16x8() {
    union { unsigned int u[4]; bf16x8 v; } z;
    z.u[0] = z.u[1] = z.u[2] = z.u[3] = 0u;
    return z.v;
}
__device__ __forceinline__ void gload_lds16(const void* g, void* l) {
    __builtin_amdgcn_global_load_lds(
        (const __attribute__((address_space(1))) unsigned int*)g,
        (__attribute__((address_space(3))) unsigned int*)l, 16, 0, 0);
}
__device__ __forceinline__ void store_out(u16* p, float v)  { *p = f2bf(v); }
__device__ __forceinline__ void store_out(float* p, float v){ *p = v; }

// ================= fused pre-pass (1 launch) =================

__device__ __forceinline__ void do_cvt(
    const float* __restrict__ in, u16* __restrict__ out, int blk)
{
    int i = (blk * 256 + (int)threadIdx.x) * 8;
    float4 a = *(const float4*)(in + i);
    float4 b = *(const float4*)(in + i + 4);
    u16x8 o;
    o[0] = f2bf(a.x); o[1] = f2bf(a.y); o[2] = f2bf(a.z); o[3] = f2bf(a.w);
    o[4] = f2bf(b.x); o[5] = f2bf(b.y); o[6] = f2bf(b.z); o[7] = f2bf(b.w);
    *(u16x8*)(out + i) = o;
}

__device__ __forceinline__ void do_transpose(
    const float* __restrict__ in, u16* __restrict__ out, int K, int F, int t)
{
    __shared__ u16 tt[32][33];
    int fb = t % (F >> 5), kb = t / (F >> 5);
    int f0 = fb << 5, k0 = kb << 5;
    int lx = threadIdx.x & 31;
    int ly = threadIdx.x >> 5;
#pragma unroll
    for (int i = 0; i < 4; ++i) {
        int k = ly + i * 8;
        tt[k][lx] = f2bf(in[(size_t)(k0 + k) * F + f0 + lx]);
    }
    __syncthreads();
#pragma unroll
    for (int i = 0; i < 4; ++i) {
        int fy = ly + i * 8;
        out[(size_t)(f0 + fy) * K + k0 + lx] = tt[lx][fy];
    }
}

__device__ __forceinline__ void do_prep_d(
    const float* __restrict__ d, u16* __restrict__ o, int K, int blk)
{
    int i = blk * 256 + (int)threadIdx.x;
    int r = i & 7;
    int k = (i >> 3) % K;
    int t = i / (K * 8);
    o[i] = f2bf(d[((size_t)k * 8 + r) * 8 + t]);
}

__device__ __forceinline__ void do_prep_u(
    const float* __restrict__ u, u16* __restrict__ o, int F, int blk)
{
    int i = blk * 256 + (int)threadIdx.x;
    int r = i & 7;
    int f = (i >> 3) % F;
    int t = i / (F * 8);
    o[i] = f2bf(u[((size_t)r * F + f) * 8 + t] * 2.0f);
}

__global__ __launch_bounds__(256) void prep_all(
    const float* x, const float* k0, const float* k1, const float* k2,
    const float* d0, const float* d1, const float* d2,
    const float* u0, const float* u1, const float* u2,
    u16* xb, u16* k0T, u16* k1T, u16* k2T,
    u16* dS0, u16* dS1, u16* dS2, u16* uS0, u16* uS1, u16* uS2)
{
    int b = blockIdx.x;
    if      (b < 4096)  do_cvt(x, xb, b);
    else if (b < 6144)  do_transpose(k0, k0T, 1024, 2048, b - 4096);
    else if (b < 10240) do_transpose(k1, k1T, 2048, 2048, b - 6144);
    else if (b < 12288) do_transpose(k2, k2T, 2048, 1024, b - 10240);
    else if (b < 12544) do_prep_d(d0, dS0, 1024, b - 12288);
    else if (b < 13056) do_prep_d(d1, dS1, 2048, b - 12544);
    else if (b < 13568) do_prep_d(d2, dS2, 2048, b - 13056);
    else if (b < 14080) do_prep_u(u0, uS0, 2048, b - 13568);
    else if (b < 14592) do_prep_u(u1, uS1, 2048, b - 14080);
    else                do_prep_u(u2, uS2, 1024, b - 14592);
}

// ---------------- LoRA down-projection (unchanged) ----------------
__global__ __launch_bounds__(256) void lora_down(
    const u16* __restrict__ H, const u16* __restrict__ dS,
    u16* __restrict__ Aout, int K)
{
    int gt   = blockIdx.x * 256 + threadIdx.x;
    int row  = gt >> 3;
    int oct  = gt & 7;
    int task = row >> 10;
    const u16* hrow = H  + (size_t)row * K;
    const u16* dt   = dS + (size_t)task * K * 8;
    float acc[8];
#pragma unroll
    for (int r = 0; r < 8; ++r) acc[r] = 0.f;
    int kpt  = K >> 3;
    int kbeg = oct * kpt;
    for (int kk = kbeg; kk < kbeg + kpt; kk += 8) {
        u16x8 h8 = *(const u16x8*)(hrow + kk);
#pragma unroll
        for (int j = 0; j < 8; ++j) {
            float hv = bf2f(h8[j]);
            u16x8 dv = *(const u16x8*)(dt + (size_t)(kk + j) * 8);
#pragma unroll
            for (int r = 0; r < 8; ++r)
                acc[r] += hv * bf2f(dv[r]);
        }
    }
#pragma unroll
    for (int r = 0; r < 8; ++r) {
        acc[r] += __shfl_xor(acc[r], 1);
        acc[r] += __shfl_xor(acc[r], 2);
        acc[r] += __shfl_xor(acc[r], 4);
    }
    if (oct == 0) {
        u16x8 o;
#pragma unroll
        for (int r = 0; r < 8; ++r) o[r] = f2bf(acc[r]);
        *(u16x8*)(Aout + (size_t)row * 8) = o;
    }
}

// ============ BMxBN 4-phase GEMM + rank-8 LoRA epilogue ===================
// R11: R9 schedule with phase pairs MERGED (8 -> 4 phases/iter, half the
// barriers) and NO setprio (R10 within-probe A/B: setprio -5us here).
// Swizzle unchanged (0 conflicts since R3): chunk kc of row r at slot
// kc^(r&7); stage via pre-swizzled global source; read slot=(ks*4+lg)^(l15&7).
//
// Merged schedule (iter i: buf0 tile t0=2i in Q0/Q1, buf1 tile t1=2i+1 in
// Q2/Q3; t2=2i+2, t3=2i+3):
//  Q0: reads buf0.{A0,B0,B1}; MFMA (0,0),(0,1); stage buf1.{A1,B1}<-t1
//  Q1: reads buf0.{A1};       MFMA (1,0),(1,1); stage buf0.{A0,B0}<-t2; vmcnt
//  Q2: reads buf1.{A0,B0,B1}; MFMA (0,0),(0,1); stage buf0.{A1,B1}<-t2
//  Q3: reads buf1.{A1};       MFMA (1,0),(1,1); stage buf1.{A0,B0}<-t3; vmcnt
// vmcnt(SAL+SBL) leaves own-phase loads in flight, retires the 2 prior
// phases' loads:
//  @Q1: retires prev-Q3 (buf1.A0,B0) + Q0 (buf1.A1,B1) = buf1 tile, first
//       read at Q2 ✓.  @Q3: retires Q1+Q2 = buf0 tile, read next-Q0 ✓.
// Overwrite hazards (>=1 barrier between reader phase end and stage issue):
//  Q0 stages buf1.A1 (read prev-Q3 ✓), B1 (read prev-Q2 ✓); Q1 stages
//  buf0.A0,B0 (read Q0 ✓); Q2 stages buf0.A1 (read Q1 ✓), B1 (read Q0 ✓);
//  Q3 stages buf1.A0,B0 (read Q2 ✓). A phase's ds_reads are all lgkm-retired
//  before its own MFMAs issue (operand dependence), hence before PHASE_END.
// Tail iter: Q0 still stages buf1.{A1,B1}; Q1 drains vmcnt(0) (buf1 full);
// Q2/Q3 stage nothing.

#define WVMC do { if constexpr (SAL + SBL == 4) { \
                    asm volatile("s_waitcnt vmcnt(4)" ::: "memory"); \
                  } else { \
                    asm volatile("s_waitcnt vmcnt(3)" ::: "memory"); } } while (0)
#define WVM0  asm volatile("s_waitcnt vmcnt(0)" ::: "memory")
#define PHASE_END do { __builtin_amdgcn_sched_barrier(0); \
                       __builtin_amdgcn_s_barrier(); } while (0)

#define DS_A(c, mh) do { \
    _Pragma("unroll") for (int mm = 0; mm < NMH; ++mm) \
    _Pragma("unroll") for (int ks = 0; ks < 2; ++ks) \
        aF[mm][ks] = *(const bf16x8*)((const char*)&sA[c][0] + \
                       arowb + ((mh)*NMH+mm)*4096 + (ks ? cb1 : cb0)); } while (0)

#define DS_B(c, nh, bset) do { \
    _Pragma("unroll") for (int nn = 0; nn < NBH; ++nn) \
    _Pragma("unroll") for (int ks = 0; ks < 2; ++ks) \
        bset[nn][ks] = *(const bf16x8*)((const char*)&sB[c][0] + \
                       browb + ((nh)*NBH+nn)*8192 + (ks ? cb1 : cb0)); } while (0)

#define MFMAQ(mh, nh, bset) do { \
    _Pragma("unroll") for (int ks = 0; ks < 2; ++ks) \
    _Pragma("unroll") for (int mm = 0; mm < NMH; ++mm) \
    _Pragma("unroll") for (int nn = 0; nn < NBH; ++nn) \
        acc[(mh)*NMH+mm][(nh)*NBH+nn] = __builtin_amdgcn_mfma_f32_16x16x32_bf16( \
            aF[mm][ks], bset[nn][ks], acc[(mh)*NMH+mm][(nh)*NBH+nn], 0, 0, 0); } while (0)

#define STAGE_A(c, h, kt) do { \
    _Pragma("unroll") for (int s = 0; s < SAL; ++s) \
        gload_lds16((const char*)A + (size_t)(unsigned)(aBase + \
                      ((h)*BMH + s*64)*(K*2) + (kt)*128), \
                    (char*)&sA[c][0] + (h)*(BMH*128) + s*8192 + tdst); } while (0)

#define STAGE_B(c, h, kt) do { \
    _Pragma("unroll") for (int s = 0; s < SBL; ++s) \
        gload_lds16((const char*)BT + (size_t)(unsigned)(bBase + \
                      ((h)*BNH + s*64)*(K*2) + (kt)*128), \
                    (char*)&sB[c][0] + (h)*(BNH*128) + s*8192 + tdst); } while (0)

template<int RELU, int BM, int BN, typename OUT_T>
__global__ __launch_bounds__(512, 2) void gemm_lora8(
    const u16* __restrict__ A, const u16* __restrict__ BT,
    const u16* __restrict__ ALR, const u16* __restrict__ US,
    const float* __restrict__ bias, OUT_T* __restrict__ C,
    int N, int K)
{
    constexpr int SAL = BM / 128;   // stage loads/thread per A-half
    constexpr int SBL = BN / 128;   // stage loads/thread per B-half
    constexpr int NMH = BM / 64;    // 16-row m-blocks per wave per A-half
    constexpr int NMB = BM / 32;    // m-blocks per wave total
    constexpr int NBH = BN / 128;   // 16-col n-blocks per wave per B-half
    constexpr int NBN = BN / 64;    // n-blocks per wave total
    constexpr int BMH = BM / 2;     // rows per A-half
    constexpr int BNH = BN / 2;     // rows per B-half

    __shared__ __align__(16) u16 sA[2][BM * 64];
    __shared__ __align__(16) u16 sB[2][BN * 64];

    const int tid  = threadIdx.x;
    const int lane = tid & 63;
    const int wave = tid >> 6;
    const int wr   = wave >> 2;   // 0..1
    const int wc   = wave & 3;    // 0..3
    const int l15  = lane & 15;
    const int lg   = lane >> 4;

    // bijective XCD swizzle (m204)
    const int nwg = gridDim.x;
    const int orig = blockIdx.x;
    const int q = nwg >> 3, r = nwg & 7;
    const int x = orig & 7, o = orig >> 3;
    const int wg = (x < r ? x * (q + 1) : r * (q + 1) + (x - r) * q) + o;
    const int nbn  = N / BN;
    const int bm   = wg / nbn;
    const int bn   = wg % nbn;
    const int brow = bm * BM;
    const int bcol = bn * BN;
    const int task = brow >> 10;

    // staging addressing (kc independent of h,s: all half offsets == 0 mod 8)
    const int trow = tid >> 3;                       // 0..63
    const int tkc  = (tid & 7) ^ (trow & 7);
    const int tdst = tid * 16;
    const int aBase = (brow + trow) * (K * 2) + tkc * 16;
    const int bBase = (bcol + trow) * (K * 2) + tkc * 16;

    // ds_read column bases: slot = (ks*4+lg) ^ (l15&7)
    const int rp    = l15 & 7;
    const int cb0   = ((lg ^ (rp & 3)) << 4) | ((rp & 4) << 4);  // ks=0
    const int cb1   = cb0 ^ 64;                                   // ks=1
    const int arowb = (wr * 16 + l15) * 128;
    const int browb = (wc * 16 + l15) * 128;

    f32x4 acc[NMB][NBN];
    const f32x4 zf = {0.f, 0.f, 0.f, 0.f};
#pragma unroll
    for (int m = 0; m < NMB; ++m)
#pragma unroll
        for (int n = 0; n < NBN; ++n) acc[m][n] = zf;

    bf16x8 aF[NMH][2], bF0[NBH][2], bF1[NBH][2];

    // prologue: buf0 <- t0 (4 halves), buf1 <- t1 A0,B0
    STAGE_A(0, 0, 0); STAGE_B(0, 0, 0); STAGE_A(0, 1, 0); STAGE_B(0, 1, 0);
    STAGE_A(1, 0, 1); STAGE_B(1, 0, 1);
    WVMC;              // buf0 tile landed; buf1 A0,B0 stay in flight
    PHASE_END;

    const int iters = K >> 7;
#pragma unroll 1
    for (int i = 0; i < iters; ++i) {
        const int t1 = 2 * i + 1, t2 = 2 * i + 2, t3 = 2 * i + 3;
        const bool nl = (i + 1 < iters);

        // Q0: quads (0,0),(0,1) of buf0 ; stage buf1.{A1,B1} <- t1
        STAGE_A(1, 1, t1);
        STAGE_B(1, 1, t1);
        DS_A(0, 0); DS_B(0, 0, bF0); DS_B(0, 1, bF1);
        MFMAQ(0, 0, bF0); MFMAQ(0, 1, bF1);
        PHASE_END;
        // Q1: quads (1,0),(1,1) of buf0 ; stage buf0.{A0,B0} <- t2 ; vmcnt
        if (nl) { STAGE_A(0, 0, t2); STAGE_B(0, 0, t2); }
        DS_A(0, 1);
        MFMAQ(1, 0, bF0); MFMAQ(1, 1, bF1);
        if (nl) { WVMC; } else { WVM0; }
        PHASE_END;
        // Q2: quads (0,0),(0,1) of buf1 ; stage buf0.{A1,B1} <- t2
        if (nl) { STAGE_A(0, 1, t2); STAGE_B(0, 1, t2); }
        DS_A(1, 0); DS_B(1, 0, bF0); DS_B(1, 1, bF1);
        MFMAQ(0, 0, bF0); MFMAQ(0, 1, bF1);
        PHASE_END;
        // Q3: quads (1,0),(1,1) of buf1 ; stage buf1.{A0,B0} <- t3 ; vmcnt
        if (nl) { STAGE_A(1, 0, t3); STAGE_B(1, 0, t3); }
        DS_A(1, 1);
        MFMAQ(1, 0, bF0); MFMAQ(1, 1, bF1);
        if (nl) { WVMC; } else { WVM0; }
        PHASE_END;
    }

    // rank-8 LoRA delta: one extra MFMA round (k 0..7 valid, lanes lg>0 zero)
    bf16x8 z8 = zero_bf16x8();
    bf16x8 bU[NBN];
#pragma unroll
    for (int n = 0; n < NBN; ++n) {
        int col = bcol + n * 64 + wc * 16 + l15;
        bU[n] = (lg == 0) ? *(const bf16x8*)(US + ((size_t)task * N + col) * 8) : z8;
    }
#pragma unroll
    for (int m = 0; m < NMB; ++m) {
        int row = brow + m * 32 + wr * 16 + l15;
        bf16x8 aL = (lg == 0) ? *(const bf16x8*)(ALR + (size_t)row * 8) : z8;
#pragma unroll
        for (int n = 0; n < NBN; ++n)
            acc[m][n] = __builtin_amdgcn_mfma_f32_16x16x32_bf16(
                aL, bU[n], acc[m][n], 0, 0, 0);
    }

    // bias (+ReLU) + store; C/D: col = lane&15, row = lg*4 + reg
#pragma unroll
    for (int n = 0; n < NBN; ++n) {
        int col  = bcol + n * 64 + wc * 16 + l15;
        float bv = bias[col];
#pragma unroll
        for (int m = 0; m < NMB; ++m) {
            int row0 = brow + m * 32 + wr * 16 + lg * 4;
#pragma unroll
            for (int rr = 0; rr < 4; ++rr) {
                float v = acc[m][n][rr] + bv;
                if (RELU) v = fmaxf(v, 0.0f);
                store_out(&C[(size_t)(row0 + rr) * N + col], v);
            }
        }
    }
}

// ---------------- launch ----------------

extern "C" void kernel_launch(void* const* d_in, const int* in_sizes, int n_in,
                              void* d_out, int out_size, void* d_ws, size_t ws_size,
                              hipStream_t stream) {
    const float* x  = (const float*)d_in[0];
    const float* k0 = (const float*)d_in[1];
    const float* b0 = (const float*)d_in[2];
    const float* d0 = (const float*)d_in[3];
    const float* u0 = (const float*)d_in[4];
    const float* k1 = (const float*)d_in[5];
    const float* b1 = (const float*)d_in[6];
    const float* d1 = (const float*)d_in[7];
    const float* u1 = (const float*)d_in[8];
    const float* k2 = (const float*)d_in[9];
    const float* b2 = (const float*)d_in[10];
    const float* d2 = (const float*)d_in[11];
    const float* u2 = (const float*)d_in[12];

    const int T = 8, B = 1024, D = 1024, H1 = 2048, H2 = 2048, H3 = 1024;
    const int M = T * B;

    u16* w = (u16*)d_ws;
    size_t off = 0;
    u16* xb  = w + off; off += (size_t)M * D;
    u16* k0T = w + off; off += (size_t)H1 * D;
    u16* k1T = w + off; off += (size_t)H2 * H1;
    u16* k2T = w + off; off += (size_t)H3 * H2;
    u16* dS0 = w + off; off += (size_t)T * D * 8;
    u16* dS1 = w + off; off += (size_t)T * H1 * 8;
    u16* dS2 = w + off; off += (size_t)T * H2 * 8;
    u16* uS0 = w + off; off += (size_t)T * H1 * 8;
    u16* uS1 = w + off; off += (size_t)T * H2 * 8;
    u16* uS2 = w + off; off += (size_t)T * H3 * 8;
    u16* h1  = w + off; off += (size_t)M * H1;
    u16* h2  = w + off; off += (size_t)M * H2;
    u16* Ab  = w + off; off += (size_t)M * 8;
    (void)ws_size; (void)in_sizes; (void)n_in; (void)out_size;

    prep_all<<<14848, 256, 0, stream>>>(
        x, k0, k1, k2, d0, d1, d2, u0, u1, u2,
        xb, k0T, k1T, k2T, dS0, dS1, dS2, uS0, uS1, uS2);

    // layer 0 (BM=256,BN=256: 32x8 = 256 blocks)
    lora_down<<<(M * 8) / 256, 256, 0, stream>>>(xb, dS0, Ab, D);
    gemm_lora8<1, 256, 256, u16><<<(M / 256) * (H1 / 256), 512, 0, stream>>>(
        xb, k0T, Ab, uS0, b0, h1, H1, D);
    // layer 1 (BM=256,BN=256: 32x8 = 256 blocks)
    lora_down<<<(M * 8) / 256, 256, 0, stream>>>(h1, dS1, Ab, H1);
    gemm_lora8<1, 256, 256, u16><<<(M / 256) * (H2 / 256), 512, 0, stream>>>(
        h1, k1T, Ab, uS1, b1, h2, H2, H1);
    // layer 2 (no relu, fp32 out; BM=128,BN=256: 64x4 = 256 blocks)
    lora_down<<<(M * 8) / 256, 256, 0, stream>>>(h2, dS2, Ab, H2);
    gemm_lora8<0, 128, 256, float><<<(M / 128) * (H3 / 256), 512, 0, stream>>>(
        h2, k2T, Ab, uS2, b2, (float*)d_out, H3, H2);
}

// Round 12
// 259.992 us; speedup vs baseline: 1.0438x; 1.0379x over previous
//
#include <hip/hip_runtime.h>

typedef unsigned short u16;
typedef __attribute__((ext_vector_type(8))) __bf16 bf16x8;
typedef __attribute__((ext_vector_type(8))) unsigned short u16x8;
typedef __attribute__((ext_vector_type(4))) float f32x4;

__device__ __forceinline__ float bf2f(u16 h) {
    return __uint_as_float(((unsigned int)h) << 16);
}
__device__ __forceinline__ u16 f2bf(float f) {
    unsigned int u = __float_as_uint(f);
    u += 0x7fffu + ((u >> 16) & 1u);   // round-to-nearest-even
    return (u16)(u >> 16);
}
__device__ __forceinline__ bf16x8 zero_bf16x8() {
    union { unsigned int u[4]; bf16x8 v; } z;
    z.u[0] = z.u[1] = z.u[2] = z.u[3] = 0u;
    return z.v;
}
__device__ __forceinline__ void gload_lds16(const void* g, void* l) {
    __builtin_amdgcn_global_load_lds(
        (const __attribute__((address_space(1))) unsigned int*)g,
        (__attribute__((address_space(3))) unsigned int*)l, 16, 0, 0);
}
__device__ __forceinline__ void store_out(u16* p, float v)  { *p = f2bf(v); }
__device__ __forceinline__ void store_out(float* p, float v){ *p = v; }

// ================= fused pre-pass (1 launch) =================

__device__ __forceinline__ void do_cvt(
    const float* __restrict__ in, u16* __restrict__ out, int blk)
{
    int i = (blk * 256 + (int)threadIdx.x) * 8;
    float4 a = *(const float4*)(in + i);
    float4 b = *(const float4*)(in + i + 4);
    u16x8 o;
    o[0] = f2bf(a.x); o[1] = f2bf(a.y); o[2] = f2bf(a.z); o[3] = f2bf(a.w);
    o[4] = f2bf(b.x); o[5] = f2bf(b.y); o[6] = f2bf(b.z); o[7] = f2bf(b.w);
    *(u16x8*)(out + i) = o;
}

__device__ __forceinline__ void do_transpose(
    const float* __restrict__ in, u16* __restrict__ out, int K, int F, int t)
{
    __shared__ u16 tt[32][33];
    int fb = t % (F >> 5), kb = t / (F >> 5);
    int f0 = fb << 5, k0 = kb << 5;
    int lx = threadIdx.x & 31;
    int ly = threadIdx.x >> 5;
#pragma unroll
    for (int i = 0; i < 4; ++i) {
        int k = ly + i * 8;
        tt[k][lx] = f2bf(in[(size_t)(k0 + k) * F + f0 + lx]);
    }
    __syncthreads();
#pragma unroll
    for (int i = 0; i < 4; ++i) {
        int fy = ly + i * 8;
        out[(size_t)(f0 + fy) * K + k0 + lx] = tt[lx][fy];
    }
}

__device__ __forceinline__ void do_prep_d(
    const float* __restrict__ d, u16* __restrict__ o, int K, int blk)
{
    int i = blk * 256 + (int)threadIdx.x;
    int r = i & 7;
    int k = (i >> 3) % K;
    int t = i / (K * 8);
    o[i] = f2bf(d[((size_t)k * 8 + r) * 8 + t]);
}

__device__ __forceinline__ void do_prep_u(
    const float* __restrict__ u, u16* __restrict__ o, int F, int blk)
{
    int i = blk * 256 + (int)threadIdx.x;
    int r = i & 7;
    int f = (i >> 3) % F;
    int t = i / (F * 8);
    o[i] = f2bf(u[((size_t)r * F + f) * 8 + t] * 2.0f);
}

__global__ __launch_bounds__(256) void prep_all(
    const float* x, const float* k0, const float* k1, const float* k2,
    const float* d0, const float* d1, const float* d2,
    const float* u0, const float* u1, const float* u2,
    u16* xb, u16* k0T, u16* k1T, u16* k2T,
    u16* dS0, u16* dS1, u16* dS2, u16* uS0, u16* uS1, u16* uS2)
{
    int b = blockIdx.x;
    if      (b < 4096)  do_cvt(x, xb, b);
    else if (b < 6144)  do_transpose(k0, k0T, 1024, 2048, b - 4096);
    else if (b < 10240) do_transpose(k1, k1T, 2048, 2048, b - 6144);
    else if (b < 12288) do_transpose(k2, k2T, 2048, 1024, b - 10240);
    else if (b < 12544) do_prep_d(d0, dS0, 1024, b - 12288);
    else if (b < 13056) do_prep_d(d1, dS1, 2048, b - 12544);
    else if (b < 13568) do_prep_d(d2, dS2, 2048, b - 13056);
    else if (b < 14080) do_prep_u(u0, uS0, 2048, b - 13568);
    else if (b < 14592) do_prep_u(u1, uS1, 2048, b - 14080);
    else                do_prep_u(u2, uS2, 1024, b - 14592);
}

// ---------------- LoRA down-projection (unchanged) ----------------
__global__ __launch_bounds__(256) void lora_down(
    const u16* __restrict__ H, const u16* __restrict__ dS,
    u16* __restrict__ Aout, int K)
{
    int gt   = blockIdx.x * 256 + threadIdx.x;
    int row  = gt >> 3;
    int oct  = gt & 7;
    int task = row >> 10;
    const u16* hrow = H  + (size_t)row * K;
    const u16* dt   = dS + (size_t)task * K * 8;
    float acc[8];
#pragma unroll
    for (int r = 0; r < 8; ++r) acc[r] = 0.f;
    int kpt  = K >> 3;
    int kbeg = oct * kpt;
    for (int kk = kbeg; kk < kbeg + kpt; kk += 8) {
        u16x8 h8 = *(const u16x8*)(hrow + kk);
#pragma unroll
        for (int j = 0; j < 8; ++j) {
            float hv = bf2f(h8[j]);
            u16x8 dv = *(const u16x8*)(dt + (size_t)(kk + j) * 8);
#pragma unroll
            for (int r = 0; r < 8; ++r)
                acc[r] += hv * bf2f(dv[r]);
        }
    }
#pragma unroll
    for (int r = 0; r < 8; ++r) {
        acc[r] += __shfl_xor(acc[r], 1);
        acc[r] += __shfl_xor(acc[r], 2);
        acc[r] += __shfl_xor(acc[r], 4);
    }
    if (oct == 0) {
        u16x8 o;
#pragma unroll
        for (int r = 0; r < 8; ++r) o[r] = f2bf(acc[r]);
        *(u16x8*)(Aout + (size_t)row * 8) = o;
    }
}

// ===== BMxBN 8-phase READ-AHEAD-1 GEMM + rank-8 LoRA epilogue =============
// R12: same regs/slots/swizzle as R9, but each phase's ds_reads fetch the
// NEXT quadrant's operands (same registers, WAR after MFMA issue) so the LDS
// pipe drains under the MFMA cluster + barrier wait instead of serializing.
//   P0: mfma(0,0)b0 | rd bF1<-b0.B1   P4: mfma(0,0)b1 | rd bF1<-b1.B1
//   P1: mfma(0,1)b0 | rd aF <-b0.A1   P5: mfma(0,1)b1 | rd aF <-b1.A1
//   P2: mfma(1,0)b0 | rd --  +vmcnt   P6: mfma(1,0)b1 | rd --  +vmcnt
//   P3: mfma(1,1)b0 | rd aF<-b1.A0,   P7: mfma(1,1)b1 | rd aF<-b0.A0,
//                        bF0<-b1.B0                         bF0<-b0.B0 (t2)
// Stage slots unchanged (R9): P0 b1.A1<-t1, P1 b1.B1<-t1, P2 b0.A0<-t2,
// P3 b0.B0<-t2, P4 b0.A1<-t2, P5 b0.B1<-t2, P6 b1.A0<-t3, P7 b1.B0<-t3.
// PUBLISH SHIFT: buffers must be readable one phase earlier than R9 ->
// counted vmcnt moves to P2/P6 with value SAL (own-phase loads in flight):
//  @P2-end: outstanding prev-P6(SAL)+prev-P7(SBL)+P0(SAL)+P1(SBL)+P2(SAL);
//   vmcnt(SAL) retires through P1 = buf1 tile complete; barrier publishes;
//   first buf1 read at P3 ✓.
//  @P6-end: outstanding P2..P6; vmcnt(SAL) retires P2..P5 = buf0(t2)
//   complete; first read at P7 ✓.
// Overwrite hazards: every slot's reader consumes (lgkm-retires) its read
// >=1 barrier before the overwriting stage issues (e.g. b0.A0 read@P7,
// consumed@next-P0 MFMA, staged@P2; b1.B0 read@P3, consumed@P4, staged@P7).
// WAR reg reuse: ds_read overwrites frag regs only AFTER the MFMA cluster
// reading them has issued (program order within phase; compiler handles the
// anti-dependence). MFMA operands always read one full phase + barrier
// earlier -> lgkm wait at cluster head is already-drained.
// Tail iter: P2 drains vmcnt(0) (buf1 fully staged by P0/P1 + prev-P6/P7);
// P6 no wait (nothing outstanding); P7 skips next-tile reads.

#define WVMC do { if constexpr (SAL + SBL == 4) { \
                    asm volatile("s_waitcnt vmcnt(4)" ::: "memory"); \
                  } else { \
                    asm volatile("s_waitcnt vmcnt(3)" ::: "memory"); } } while (0)
#define WVMP do { if constexpr (SAL == 2) { \
                    asm volatile("s_waitcnt vmcnt(2)" ::: "memory"); \
                  } else { \
                    asm volatile("s_waitcnt vmcnt(1)" ::: "memory"); } } while (0)
#define WVM0  asm volatile("s_waitcnt vmcnt(0)" ::: "memory")
#define PHASE_END do { __builtin_amdgcn_sched_barrier(0); \
                       __builtin_amdgcn_s_barrier(); } while (0)

#define DS_A(c, mh) do { \
    _Pragma("unroll") for (int mm = 0; mm < NMH; ++mm) \
    _Pragma("unroll") for (int ks = 0; ks < 2; ++ks) \
        aF[mm][ks] = *(const bf16x8*)((const char*)&sA[c][0] + \
                       arowb + ((mh)*NMH+mm)*4096 + (ks ? cb1 : cb0)); } while (0)

#define DS_B(c, nh, bset) do { \
    _Pragma("unroll") for (int nn = 0; nn < NBH; ++nn) \
    _Pragma("unroll") for (int ks = 0; ks < 2; ++ks) \
        bset[nn][ks] = *(const bf16x8*)((const char*)&sB[c][0] + \
                       browb + ((nh)*NBH+nn)*8192 + (ks ? cb1 : cb0)); } while (0)

#define MFMAQ(mh, nh, bset) do { \
    _Pragma("unroll") for (int ks = 0; ks < 2; ++ks) \
    _Pragma("unroll") for (int mm = 0; mm < NMH; ++mm) \
    _Pragma("unroll") for (int nn = 0; nn < NBH; ++nn) \
        acc[(mh)*NMH+mm][(nh)*NBH+nn] = __builtin_amdgcn_mfma_f32_16x16x32_bf16( \
            aF[mm][ks], bset[nn][ks], acc[(mh)*NMH+mm][(nh)*NBH+nn], 0, 0, 0); } while (0)

#define STAGE_A(c, h, kt) do { \
    _Pragma("unroll") for (int s = 0; s < SAL; ++s) \
        gload_lds16((const char*)A + (size_t)(unsigned)(aBase + \
                      ((h)*BMH + s*64)*(K*2) + (kt)*128), \
                    (char*)&sA[c][0] + (h)*(BMH*128) + s*8192 + tdst); } while (0)

#define STAGE_B(c, h, kt) do { \
    _Pragma("unroll") for (int s = 0; s < SBL; ++s) \
        gload_lds16((const char*)BT + (size_t)(unsigned)(bBase + \
                      ((h)*BNH + s*64)*(K*2) + (kt)*128), \
                    (char*)&sB[c][0] + (h)*(BNH*128) + s*8192 + tdst); } while (0)

template<int RELU, int BM, int BN, typename OUT_T>
__global__ __launch_bounds__(512, 2) void gemm_lora8(
    const u16* __restrict__ A, const u16* __restrict__ BT,
    const u16* __restrict__ ALR, const u16* __restrict__ US,
    const float* __restrict__ bias, OUT_T* __restrict__ C,
    int N, int K)
{
    constexpr int SAL = BM / 128;   // stage loads/thread per A-half
    constexpr int SBL = BN / 128;   // stage loads/thread per B-half
    constexpr int NMH = BM / 64;    // 16-row m-blocks per wave per A-half
    constexpr int NMB = BM / 32;    // m-blocks per wave total
    constexpr int NBH = BN / 128;   // 16-col n-blocks per wave per B-half
    constexpr int NBN = BN / 64;    // n-blocks per wave total
    constexpr int BMH = BM / 2;     // rows per A-half
    constexpr int BNH = BN / 2;     // rows per B-half

    __shared__ __align__(16) u16 sA[2][BM * 64];
    __shared__ __align__(16) u16 sB[2][BN * 64];

    const int tid  = threadIdx.x;
    const int lane = tid & 63;
    const int wave = tid >> 6;
    const int wr   = wave >> 2;   // 0..1
    const int wc   = wave & 3;    // 0..3
    const int l15  = lane & 15;
    const int lg   = lane >> 4;

    // bijective XCD swizzle (m204)
    const int nwg = gridDim.x;
    const int orig = blockIdx.x;
    const int q = nwg >> 3, r = nwg & 7;
    const int x = orig & 7, o = orig >> 3;
    const int wg = (x < r ? x * (q + 1) : r * (q + 1) + (x - r) * q) + o;
    const int nbn  = N / BN;
    const int bm   = wg / nbn;
    const int bn   = wg % nbn;
    const int brow = bm * BM;
    const int bcol = bn * BN;
    const int task = brow >> 10;

    // staging addressing (kc independent of h,s: all half offsets == 0 mod 8)
    const int trow = tid >> 3;                       // 0..63
    const int tkc  = (tid & 7) ^ (trow & 7);
    const int tdst = tid * 16;
    const int aBase = (brow + trow) * (K * 2) + tkc * 16;
    const int bBase = (bcol + trow) * (K * 2) + tkc * 16;

    // ds_read column bases: slot = (ks*4+lg) ^ (l15&7)
    const int rp    = l15 & 7;
    const int cb0   = ((lg ^ (rp & 3)) << 4) | ((rp & 4) << 4);  // ks=0
    const int cb1   = cb0 ^ 64;                                   // ks=1
    const int arowb = (wr * 16 + l15) * 128;
    const int browb = (wc * 16 + l15) * 128;

    f32x4 acc[NMB][NBN];
    const f32x4 zf = {0.f, 0.f, 0.f, 0.f};
#pragma unroll
    for (int m = 0; m < NMB; ++m)
#pragma unroll
        for (int n = 0; n < NBN; ++n) acc[m][n] = zf;

    bf16x8 aF[NMH][2], bF0[NBH][2], bF1[NBH][2];

    // prologue: buf0 <- t0 (4 halves), buf1 <- t1 A0,B0
    STAGE_A(0, 0, 0); STAGE_B(0, 0, 0); STAGE_A(0, 1, 0); STAGE_B(0, 1, 0);
    STAGE_A(1, 0, 1); STAGE_B(1, 0, 1);
    WVMC;              // buf0 tile landed; buf1 A0,B0 stay in flight
    PHASE_END;
    // pre-loop reads for P0's MFMA
    DS_A(0, 0); DS_B(0, 0, bF0);

    const int iters = K >> 7;
#pragma unroll 1
    for (int i = 0; i < iters; ++i) {
        const int t1 = 2 * i + 1, t2 = 2 * i + 2, t3 = 2 * i + 3;
        const bool nl = (i + 1 < iters);

        // P0: mfma(0,0) buf0 ; stage buf1.A1<-t1 ; rd bF1<-buf0.B1
        STAGE_A(1, 1, t1);
        MFMAQ(0, 0, bF0);
        DS_B(0, 1, bF1);
        PHASE_END;
        // P1: mfma(0,1) buf0 ; stage buf1.B1<-t1 ; rd aF<-buf0.A1
        STAGE_B(1, 1, t1);
        MFMAQ(0, 1, bF1);
        DS_A(0, 1);
        PHASE_END;
        // P2: mfma(1,0) buf0 ; stage buf0.A0<-t2 ; vmcnt publishes buf1
        if (nl) STAGE_A(0, 0, t2);
        MFMAQ(1, 0, bF0);
        if (nl) { WVMP; } else { WVM0; }
        PHASE_END;
        // P3: mfma(1,1) buf0 ; stage buf0.B0<-t2 ; rd aF<-buf1.A0, bF0<-buf1.B0
        if (nl) STAGE_B(0, 0, t2);
        MFMAQ(1, 1, bF1);
        DS_A(1, 0); DS_B(1, 0, bF0);
        PHASE_END;
        // P4: mfma(0,0) buf1 ; stage buf0.A1<-t2 ; rd bF1<-buf1.B1
        if (nl) STAGE_A(0, 1, t2);
        MFMAQ(0, 0, bF0);
        DS_B(1, 1, bF1);
        PHASE_END;
        // P5: mfma(0,1) buf1 ; stage buf0.B1<-t2 ; rd aF<-buf1.A1
        if (nl) STAGE_B(0, 1, t2);
        MFMAQ(0, 1, bF1);
        DS_A(1, 1);
        PHASE_END;
        // P6: mfma(1,0) buf1 ; stage buf1.A0<-t3 ; vmcnt publishes buf0(t2)
        if (nl) STAGE_A(1, 0, t3);
        MFMAQ(1, 0, bF0);
        if (nl) { WVMP; }
        PHASE_END;
        // P7: mfma(1,1) buf1 ; stage buf1.B0<-t3 ; rd aF,bF0 <- buf0(t2)
        if (nl) STAGE_B(1, 0, t3);
        MFMAQ(1, 1, bF1);
        if (nl) { DS_A(0, 0); DS_B(0, 0, bF0); }
        PHASE_END;
    }

    // rank-8 LoRA delta: one extra MFMA round (k 0..7 valid, lanes lg>0 zero)
    bf16x8 z8 = zero_bf16x8();
    bf16x8 bU[NBN];
#pragma unroll
    for (int n = 0; n < NBN; ++n) {
        int col = bcol + n * 64 + wc * 16 + l15;
        bU[n] = (lg == 0) ? *(const bf16x8*)(US + ((size_t)task * N + col) * 8) : z8;
    }
#pragma unroll
    for (int m = 0; m < NMB; ++m) {
        int row = brow + m * 32 + wr * 16 + l15;
        bf16x8 aL = (lg == 0) ? *(const bf16x8*)(ALR + (size_t)row * 8) : z8;
#pragma unroll
        for (int n = 0; n < NBN; ++n)
            acc[m][n] = __builtin_amdgcn_mfma_f32_16x16x32_bf16(
                aL, bU[n], acc[m][n], 0, 0, 0);
    }

    // bias (+ReLU) + store; C/D: col = lane&15, row = lg*4 + reg
#pragma unroll
    for (int n = 0; n < NBN; ++n) {
        int col  = bcol + n * 64 + wc * 16 + l15;
        float bv = bias[col];
#pragma unroll
        for (int m = 0; m < NMB; ++m) {
            int row0 = brow + m * 32 + wr * 16 + lg * 4;
#pragma unroll
            for (int rr = 0; rr < 4; ++rr) {
                float v = acc[m][n][rr] + bv;
                if (RELU) v = fmaxf(v, 0.0f);
                store_out(&C[(size_t)(row0 + rr) * N + col], v);
            }
        }
    }
}

// ---------------- launch ----------------

extern "C" void kernel_launch(void* const* d_in, const int* in_sizes, int n_in,
                              void* d_out, int out_size, void* d_ws, size_t ws_size,
                              hipStream_t stream) {
    const float* x  = (const float*)d_in[0];
    const float* k0 = (const float*)d_in[1];
    const float* b0 = (const float*)d_in[2];
    const float* d0 = (const float*)d_in[3];
    const float* u0 = (const float*)d_in[4];
    const float* k1 = (const float*)d_in[5];
    const float* b1 = (const float*)d_in[6];
    const float* d1 = (const float*)d_in[7];
    const float* u1 = (const float*)d_in[8];
    const float* k2 = (const float*)d_in[9];
    const float* b2 = (const float*)d_in[10];
    const float* d2 = (const float*)d_in[11];
    const float* u2 = (const float*)d_in[12];

    const int T = 8, B = 1024, D = 1024, H1 = 2048, H2 = 2048, H3 = 1024;
    const int M = T * B;

    u16* w = (u16*)d_ws;
    size_t off = 0;
    u16* xb  = w + off; off += (size_t)M * D;
    u16* k0T = w + off; off += (size_t)H1 * D;
    u16* k1T = w + off; off += (size_t)H2 * H1;
    u16* k2T = w + off; off += (size_t)H3 * H2;
    u16* dS0 = w + off; off += (size_t)T * D * 8;
    u16* dS1 = w + off; off += (size_t)T * H1 * 8;
    u16* dS2 = w + off; off += (size_t)T * H2 * 8;
    u16* uS0 = w + off; off += (size_t)T * H1 * 8;
    u16* uS1 = w + off; off += (size_t)T * H2 * 8;
    u16* uS2 = w + off; off += (size_t)T * H3 * 8;
    u16* h1  = w + off; off += (size_t)M * H1;
    u16* h2  = w + off; off += (size_t)M * H2;
    u16* Ab  = w + off; off += (size_t)M * 8;
    (void)ws_size; (void)in_sizes; (void)n_in; (void)out_size;

    prep_all<<<14848, 256, 0, stream>>>(
        x, k0, k1, k2, d0, d1, d2, u0, u1, u2,
        xb, k0T, k1T, k2T, dS0, dS1, dS2, uS0, uS1, uS2);

    // layer 0 (BM=256,BN=256: 32x8 = 256 blocks)
    lora_down<<<(M * 8) / 256, 256, 0, stream>>>(xb, dS0, Ab, D);
    gemm_lora8<1, 256, 256, u16><<<(M / 256) * (H1 / 256), 512, 0, stream>>>(
        xb, k0T, Ab, uS0, b0, h1, H1, D);
    // layer 1 (BM=256,BN=256: 32x8 = 256 blocks)
    lora_down<<<(M * 8) / 256, 256, 0, stream>>>(h1, dS1, Ab, H1);
    gemm_lora8<1, 256, 256, u16><<<(M / 256) * (H2 / 256), 512, 0, stream>>>(
        h1, k1T, Ab, uS1, b1, h2, H2, H1);
    // layer 2 (no relu, fp32 out; BM=128,BN=256: 64x4 = 256 blocks)
    lora_down<<<(M * 8) / 256, 256, 0, stream>>>(h2, dS2, Ab, H2);
    gemm_lora8<0, 128, 256, float><<<(M / 128) * (H3 / 256), 512, 0, stream>>>(
        h2, k2T, Ab, uS2, b2, (float*)d_out, H3, H2);
}

// Round 13
// 258.858 us; speedup vs baseline: 1.0483x; 1.0044x over previous
//
#include <hip/hip_runtime.h>

typedef unsigned short u16;
typedef __attribute__((ext_vector_type(8))) __bf16 bf16x8;
typedef __attribute__((ext_vector_type(8))) unsigned short u16x8;
typedef __attribute__((ext_vector_type(4))) float f32x4;

__device__ __forceinline__ float bf2f(u16 h) {
    return __uint_as_float(((unsigned int)h) << 16);
}
__device__ __forceinline__ u16 f2bf(float f) {
    unsigned int u = __float_as_uint(f);
    u += 0x7fffu + ((u >> 16) & 1u);   // round-to-nearest-even
    return (u16)(u >> 16);
}
__device__ __forceinline__ bf16x8 zero_bf16x8() {
    union { unsigned int u[4]; bf16x8 v; } z;
    z.u[0] = z.u[1] = z.u[2] = z.u[3] = 0u;
    return z.v;
}
__device__ __forceinline__ void gload_lds16(const void* g, void* l) {
    __builtin_amdgcn_global_load_lds(
        (const __attribute__((address_space(1))) unsigned int*)g,
        (__attribute__((address_space(3))) unsigned int*)l, 16, 0, 0);
}
__device__ __forceinline__ void store_out(u16* p, float v)  { *p = f2bf(v); }
__device__ __forceinline__ void store_out(float* p, float v){ *p = v; }

// ================= fused pre-pass (1 launch) =================

__device__ __forceinline__ void do_cvt(
    const float* __restrict__ in, u16* __restrict__ out, int blk)
{
    int i = (blk * 256 + (int)threadIdx.x) * 8;
    float4 a = *(const float4*)(in + i);
    float4 b = *(const float4*)(in + i + 4);
    u16x8 o;
    o[0] = f2bf(a.x); o[1] = f2bf(a.y); o[2] = f2bf(a.z); o[3] = f2bf(a.w);
    o[4] = f2bf(b.x); o[5] = f2bf(b.y); o[6] = f2bf(b.z); o[7] = f2bf(b.w);
    *(u16x8*)(out + i) = o;
}

__device__ __forceinline__ void do_transpose(
    const float* __restrict__ in, u16* __restrict__ out, int K, int F, int t)
{
    __shared__ u16 tt[32][33];
    int fb = t % (F >> 5), kb = t / (F >> 5);
    int f0 = fb << 5, k0 = kb << 5;
    int lx = threadIdx.x & 31;
    int ly = threadIdx.x >> 5;
#pragma unroll
    for (int i = 0; i < 4; ++i) {
        int k = ly + i * 8;
        tt[k][lx] = f2bf(in[(size_t)(k0 + k) * F + f0 + lx]);
    }
    __syncthreads();
#pragma unroll
    for (int i = 0; i < 4; ++i) {
        int fy = ly + i * 8;
        out[(size_t)(f0 + fy) * K + k0 + lx] = tt[lx][fy];
    }
}

__device__ __forceinline__ void do_prep_d(
    const float* __restrict__ d, u16* __restrict__ o, int K, int blk)
{
    int i = blk * 256 + (int)threadIdx.x;
    int r = i & 7;
    int k = (i >> 3) % K;
    int t = i / (K * 8);
    o[i] = f2bf(d[((size_t)k * 8 + r) * 8 + t]);
}

__device__ __forceinline__ void do_prep_u(
    const float* __restrict__ u, u16* __restrict__ o, int F, int blk)
{
    int i = blk * 256 + (int)threadIdx.x;
    int r = i & 7;
    int f = (i >> 3) % F;
    int t = i / (F * 8);
    o[i] = f2bf(u[((size_t)r * F + f) * 8 + t] * 2.0f);
}

__global__ __launch_bounds__(256) void prep_all(
    const float* x, const float* k0, const float* k1, const float* k2,
    const float* d0, const float* d1, const float* d2,
    const float* u0, const float* u1, const float* u2,
    u16* xb, u16* k0T, u16* k1T, u16* k2T,
    u16* dS0, u16* dS1, u16* dS2, u16* uS0, u16* uS1, u16* uS2)
{
    int b = blockIdx.x;
    if      (b < 4096)  do_cvt(x, xb, b);
    else if (b < 6144)  do_transpose(k0, k0T, 1024, 2048, b - 4096);
    else if (b < 10240) do_transpose(k1, k1T, 2048, 2048, b - 6144);
    else if (b < 12288) do_transpose(k2, k2T, 2048, 1024, b - 10240);
    else if (b < 12544) do_prep_d(d0, dS0, 1024, b - 12288);
    else if (b < 13056) do_prep_d(d1, dS1, 2048, b - 12544);
    else if (b < 13568) do_prep_d(d2, dS2, 2048, b - 13056);
    else if (b < 14080) do_prep_u(u0, uS0, 2048, b - 13568);
    else if (b < 14592) do_prep_u(u1, uS1, 2048, b - 14080);
    else                do_prep_u(u2, uS2, 1024, b - 14592);
}

// ---------------- LoRA down-projection (unchanged) ----------------
__global__ __launch_bounds__(256) void lora_down(
    const u16* __restrict__ H, const u16* __restrict__ dS,
    u16* __restrict__ Aout, int K)
{
    int gt   = blockIdx.x * 256 + threadIdx.x;
    int row  = gt >> 3;
    int oct  = gt & 7;
    int task = row >> 10;
    const u16* hrow = H  + (size_t)row * K;
    const u16* dt   = dS + (size_t)task * K * 8;
    float acc[8];
#pragma unroll
    for (int r = 0; r < 8; ++r) acc[r] = 0.f;
    int kpt  = K >> 3;
    int kbeg = oct * kpt;
    for (int kk = kbeg; kk < kbeg + kpt; kk += 8) {
        u16x8 h8 = *(const u16x8*)(hrow + kk);
#pragma unroll
        for (int j = 0; j < 8; ++j) {
            float hv = bf2f(h8[j]);
            u16x8 dv = *(const u16x8*)(dt + (size_t)(kk + j) * 8);
#pragma unroll
            for (int r = 0; r < 8; ++r)
                acc[r] += hv * bf2f(dv[r]);
        }
    }
#pragma unroll
    for (int r = 0; r < 8; ++r) {
        acc[r] += __shfl_xor(acc[r], 1);
        acc[r] += __shfl_xor(acc[r], 2);
        acc[r] += __shfl_xor(acc[r], 4);
    }
    if (oct == 0) {
        u16x8 o;
#pragma unroll
        for (int r = 0; r < 8; ++r) o[r] = f2bf(acc[r]);
        *(u16x8*)(Aout + (size_t)row * 8) = o;
    }
}

// ===== BMxBN 8-phase READ-AHEAD-1 GEMM + rank-8 LoRA epilogue =============
// R13: R12 schedule unchanged; template gains WPEU (min waves/EU for
// __launch_bounds__) and the (128,128) instantiation:
//   L2 runs BM=BN=128, 8 waves, LDS = 64 KiB -> 2 BLOCKS/CU (independent
//   barriers; cross-block MFMA/LDS overlap replaces intra-block pipelining).
//   WPEU=4 caps regs at 128/wave (acc 32 AGPR + frags 32 + addr ~= fits).
// vmcnt generalization (2 loads per A-half SAL, per B-half SBL):
//   prologue wait = SAL+SBL (t1.A0,B0 in flight): 4 / 3 / 2.
//   WVMP at P2/P6 = vmcnt(SAL): own-phase stage in flight, retires all
//   older -> publishes the tile first read next phase (re-derived R12).
// Slot map, swizzle (0 conflicts), hazards: unchanged from R12.

#define WVMC do { if constexpr (SAL + SBL == 4) { \
                    asm volatile("s_waitcnt vmcnt(4)" ::: "memory"); \
                  } else if constexpr (SAL + SBL == 3) { \
                    asm volatile("s_waitcnt vmcnt(3)" ::: "memory"); \
                  } else { \
                    asm volatile("s_waitcnt vmcnt(2)" ::: "memory"); } } while (0)
#define WVMP do { if constexpr (SAL == 2) { \
                    asm volatile("s_waitcnt vmcnt(2)" ::: "memory"); \
                  } else { \
                    asm volatile("s_waitcnt vmcnt(1)" ::: "memory"); } } while (0)
#define WVM0  asm volatile("s_waitcnt vmcnt(0)" ::: "memory")
#define PHASE_END do { __builtin_amdgcn_sched_barrier(0); \
                       __builtin_amdgcn_s_barrier(); } while (0)

#define DS_A(c, mh) do { \
    _Pragma("unroll") for (int mm = 0; mm < NMH; ++mm) \
    _Pragma("unroll") for (int ks = 0; ks < 2; ++ks) \
        aF[mm][ks] = *(const bf16x8*)((const char*)&sA[c][0] + \
                       arowb + ((mh)*NMH+mm)*4096 + (ks ? cb1 : cb0)); } while (0)

#define DS_B(c, nh, bset) do { \
    _Pragma("unroll") for (int nn = 0; nn < NBH; ++nn) \
    _Pragma("unroll") for (int ks = 0; ks < 2; ++ks) \
        bset[nn][ks] = *(const bf16x8*)((const char*)&sB[c][0] + \
                       browb + ((nh)*NBH+nn)*8192 + (ks ? cb1 : cb0)); } while (0)

#define MFMAQ(mh, nh, bset) do { \
    _Pragma("unroll") for (int ks = 0; ks < 2; ++ks) \
    _Pragma("unroll") for (int mm = 0; mm < NMH; ++mm) \
    _Pragma("unroll") for (int nn = 0; nn < NBH; ++nn) \
        acc[(mh)*NMH+mm][(nh)*NBH+nn] = __builtin_amdgcn_mfma_f32_16x16x32_bf16( \
            aF[mm][ks], bset[nn][ks], acc[(mh)*NMH+mm][(nh)*NBH+nn], 0, 0, 0); } while (0)

#define STAGE_A(c, h, kt) do { \
    _Pragma("unroll") for (int s = 0; s < SAL; ++s) \
        gload_lds16((const char*)A + (size_t)(unsigned)(aBase + \
                      ((h)*BMH + s*64)*(K*2) + (kt)*128), \
                    (char*)&sA[c][0] + (h)*(BMH*128) + s*8192 + tdst); } while (0)

#define STAGE_B(c, h, kt) do { \
    _Pragma("unroll") for (int s = 0; s < SBL; ++s) \
        gload_lds16((const char*)BT + (size_t)(unsigned)(bBase + \
                      ((h)*BNH + s*64)*(K*2) + (kt)*128), \
                    (char*)&sB[c][0] + (h)*(BNH*128) + s*8192 + tdst); } while (0)

template<int RELU, int BM, int BN, int WPEU, typename OUT_T>
__global__ __launch_bounds__(512, WPEU) void gemm_lora8(
    const u16* __restrict__ A, const u16* __restrict__ BT,
    const u16* __restrict__ ALR, const u16* __restrict__ US,
    const float* __restrict__ bias, OUT_T* __restrict__ C,
    int N, int K)
{
    constexpr int SAL = BM / 128;   // stage loads/thread per A-half
    constexpr int SBL = BN / 128;   // stage loads/thread per B-half
    constexpr int NMH = BM / 64;    // 16-row m-blocks per wave per A-half
    constexpr int NMB = BM / 32;    // m-blocks per wave total
    constexpr int NBH = BN / 128;   // 16-col n-blocks per wave per B-half
    constexpr int NBN = BN / 64;    // n-blocks per wave total
    constexpr int BMH = BM / 2;     // rows per A-half
    constexpr int BNH = BN / 2;     // rows per B-half

    __shared__ __align__(16) u16 sA[2][BM * 64];
    __shared__ __align__(16) u16 sB[2][BN * 64];

    const int tid  = threadIdx.x;
    const int lane = tid & 63;
    const int wave = tid >> 6;
    const int wr   = wave >> 2;   // 0..1
    const int wc   = wave & 3;    // 0..3
    const int l15  = lane & 15;
    const int lg   = lane >> 4;

    // bijective XCD swizzle (m204)
    const int nwg = gridDim.x;
    const int orig = blockIdx.x;
    const int q = nwg >> 3, r = nwg & 7;
    const int x = orig & 7, o = orig >> 3;
    const int wg = (x < r ? x * (q + 1) : r * (q + 1) + (x - r) * q) + o;
    const int nbn  = N / BN;
    const int bm   = wg / nbn;
    const int bn   = wg % nbn;
    const int brow = bm * BM;
    const int bcol = bn * BN;
    const int task = brow >> 10;

    // staging addressing (kc independent of h,s: all half offsets == 0 mod 8)
    const int trow = tid >> 3;                       // 0..63
    const int tkc  = (tid & 7) ^ (trow & 7);
    const int tdst = tid * 16;
    const int aBase = (brow + trow) * (K * 2) + tkc * 16;
    const int bBase = (bcol + trow) * (K * 2) + tkc * 16;

    // ds_read column bases: slot = (ks*4+lg) ^ (l15&7)
    const int rp    = l15 & 7;
    const int cb0   = ((lg ^ (rp & 3)) << 4) | ((rp & 4) << 4);  // ks=0
    const int cb1   = cb0 ^ 64;                                   // ks=1
    const int arowb = (wr * 16 + l15) * 128;
    const int browb = (wc * 16 + l15) * 128;

    f32x4 acc[NMB][NBN];
    const f32x4 zf = {0.f, 0.f, 0.f, 0.f};
#pragma unroll
    for (int m = 0; m < NMB; ++m)
#pragma unroll
        for (int n = 0; n < NBN; ++n) acc[m][n] = zf;

    bf16x8 aF[NMH][2], bF0[NBH][2], bF1[NBH][2];

    // prologue: buf0 <- t0 (4 halves), buf1 <- t1 A0,B0
    STAGE_A(0, 0, 0); STAGE_B(0, 0, 0); STAGE_A(0, 1, 0); STAGE_B(0, 1, 0);
    STAGE_A(1, 0, 1); STAGE_B(1, 0, 1);
    WVMC;              // buf0 tile landed; buf1 A0,B0 stay in flight
    PHASE_END;
    // pre-loop reads for P0's MFMA
    DS_A(0, 0); DS_B(0, 0, bF0);

    const int iters = K >> 7;
#pragma unroll 1
    for (int i = 0; i < iters; ++i) {
        const int t1 = 2 * i + 1, t2 = 2 * i + 2, t3 = 2 * i + 3;
        const bool nl = (i + 1 < iters);

        // P0: mfma(0,0) buf0 ; stage buf1.A1<-t1 ; rd bF1<-buf0.B1
        STAGE_A(1, 1, t1);
        MFMAQ(0, 0, bF0);
        DS_B(0, 1, bF1);
        PHASE_END;
        // P1: mfma(0,1) buf0 ; stage buf1.B1<-t1 ; rd aF<-buf0.A1
        STAGE_B(1, 1, t1);
        MFMAQ(0, 1, bF1);
        DS_A(0, 1);
        PHASE_END;
        // P2: mfma(1,0) buf0 ; stage buf0.A0<-t2 ; vmcnt publishes buf1
        if (nl) STAGE_A(0, 0, t2);
        MFMAQ(1, 0, bF0);
        if (nl) { WVMP; } else { WVM0; }
        PHASE_END;
        // P3: mfma(1,1) buf0 ; stage buf0.B0<-t2 ; rd aF<-buf1.A0, bF0<-buf1.B0
        if (nl) STAGE_B(0, 0, t2);
        MFMAQ(1, 1, bF1);
        DS_A(1, 0); DS_B(1, 0, bF0);
        PHASE_END;
        // P4: mfma(0,0) buf1 ; stage buf0.A1<-t2 ; rd bF1<-buf1.B1
        if (nl) STAGE_A(0, 1, t2);
        MFMAQ(0, 0, bF0);
        DS_B(1, 1, bF1);
        PHASE_END;
        // P5: mfma(0,1) buf1 ; stage buf0.B1<-t2 ; rd aF<-buf1.A1
        if (nl) STAGE_B(0, 1, t2);
        MFMAQ(0, 1, bF1);
        DS_A(1, 1);
        PHASE_END;
        // P6: mfma(1,0) buf1 ; stage buf1.A0<-t3 ; vmcnt publishes buf0(t2)
        if (nl) STAGE_A(1, 0, t3);
        MFMAQ(1, 0, bF0);
        if (nl) { WVMP; }
        PHASE_END;
        // P7: mfma(1,1) buf1 ; stage buf1.B0<-t3 ; rd aF,bF0 <- buf0(t2)
        if (nl) STAGE_B(1, 0, t3);
        MFMAQ(1, 1, bF1);
        if (nl) { DS_A(0, 0); DS_B(0, 0, bF0); }
        PHASE_END;
    }

    // rank-8 LoRA delta: one extra MFMA round (k 0..7 valid, lanes lg>0 zero)
    bf16x8 z8 = zero_bf16x8();
    bf16x8 bU[NBN];
#pragma unroll
    for (int n = 0; n < NBN; ++n) {
        int col = bcol + n * 64 + wc * 16 + l15;
        bU[n] = (lg == 0) ? *(const bf16x8*)(US + ((size_t)task * N + col) * 8) : z8;
    }
#pragma unroll
    for (int m = 0; m < NMB; ++m) {
        int row = brow + m * 32 + wr * 16 + l15;
        bf16x8 aL = (lg == 0) ? *(const bf16x8*)(ALR + (size_t)row * 8) : z8;
#pragma unroll
        for (int n = 0; n < NBN; ++n)
            acc[m][n] = __builtin_amdgcn_mfma_f32_16x16x32_bf16(
                aL, bU[n], acc[m][n], 0, 0, 0);
    }

    // bias (+ReLU) + store; C/D: col = lane&15, row = lg*4 + reg
#pragma unroll
    for (int n = 0; n < NBN; ++n) {
        int col  = bcol + n * 64 + wc * 16 + l15;
        float bv = bias[col];
#pragma unroll
        for (int m = 0; m < NMB; ++m) {
            int row0 = brow + m * 32 + wr * 16 + lg * 4;
#pragma unroll
            for (int rr = 0; rr < 4; ++rr) {
                float v = acc[m][n][rr] + bv;
                if (RELU) v = fmaxf(v, 0.0f);
                store_out(&C[(size_t)(row0 + rr) * N + col], v);
            }
        }
    }
}

// ---------------- launch ----------------

extern "C" void kernel_launch(void* const* d_in, const int* in_sizes, int n_in,
                              void* d_out, int out_size, void* d_ws, size_t ws_size,
                              hipStream_t stream) {
    const float* x  = (const float*)d_in[0];
    const float* k0 = (const float*)d_in[1];
    const float* b0 = (const float*)d_in[2];
    const float* d0 = (const float*)d_in[3];
    const float* u0 = (const float*)d_in[4];
    const float* k1 = (const float*)d_in[5];
    const float* b1 = (const float*)d_in[6];
    const float* d1 = (const float*)d_in[7];
    const float* u1 = (const float*)d_in[8];
    const float* k2 = (const float*)d_in[9];
    const float* b2 = (const float*)d_in[10];
    const float* d2 = (const float*)d_in[11];
    const float* u2 = (const float*)d_in[12];

    const int T = 8, B = 1024, D = 1024, H1 = 2048, H2 = 2048, H3 = 1024;
    const int M = T * B;

    u16* w = (u16*)d_ws;
    size_t off = 0;
    u16* xb  = w + off; off += (size_t)M * D;
    u16* k0T = w + off; off += (size_t)H1 * D;
    u16* k1T = w + off; off += (size_t)H2 * H1;
    u16* k2T = w + off; off += (size_t)H3 * H2;
    u16* dS0 = w + off; off += (size_t)T * D * 8;
    u16* dS1 = w + off; off += (size_t)T * H1 * 8;
    u16* dS2 = w + off; off += (size_t)T * H2 * 8;
    u16* uS0 = w + off; off += (size_t)T * H1 * 8;
    u16* uS1 = w + off; off += (size_t)T * H2 * 8;
    u16* uS2 = w + off; off += (size_t)T * H3 * 8;
    u16* h1  = w + off; off += (size_t)M * H1;
    u16* h2  = w + off; off += (size_t)M * H2;
    u16* Ab  = w + off; off += (size_t)M * 8;
    (void)ws_size; (void)in_sizes; (void)n_in; (void)out_size;

    prep_all<<<14848, 256, 0, stream>>>(
        x, k0, k1, k2, d0, d1, d2, u0, u1, u2,
        xb, k0T, k1T, k2T, dS0, dS1, dS2, uS0, uS1, uS2);

    // layer 0 (BM=256,BN=256: 32x8 = 256 blocks, 1 block/CU)
    lora_down<<<(M * 8) / 256, 256, 0, stream>>>(xb, dS0, Ab, D);
    gemm_lora8<1, 256, 256, 2, u16><<<(M / 256) * (H1 / 256), 512, 0, stream>>>(
        xb, k0T, Ab, uS0, b0, h1, H1, D);
    // layer 1 (BM=256,BN=256: 32x8 = 256 blocks, 1 block/CU)
    lora_down<<<(M * 8) / 256, 256, 0, stream>>>(h1, dS1, Ab, H1);
    gemm_lora8<1, 256, 256, 2, u16><<<(M / 256) * (H2 / 256), 512, 0, stream>>>(
        h1, k1T, Ab, uS1, b1, h2, H2, H1);
    // layer 2 (no relu, fp32 out; BM=BN=128: 64x8 = 512 blocks, 2 blocks/CU,
    // 64 KiB LDS, WPEU=4 caps regs at 128/wave for 4 waves/SIMD residency)
    lora_down<<<(M * 8) / 256, 256, 0, stream>>>(h2, dS2, Ab, H2);
    gemm_lora8<0, 128, 128, 4, float><<<(M / 128) * (H3 / 128), 512, 0, stream>>>(
        h2, k2T, Ab, uS2, b2, (float*)d_out, H3, H2);
}